// Round 8
// baseline (387.740 us; speedup 1.0000x reference)
//
#include <hip/hip_runtime.h>
#include <math.h>

#define DEVFN static __device__ __forceinline__

static constexpr int BB = 8, VV = 13, HH = 32, WW = 64;
static constexpr int NPLANE = HH * WW;        // 2048
static constexpr int NF = BB * VV * NPLANE;   // 212992
static constexpr int NHB = BB * 65 * NPLANE;  // 1064960

static constexpr float DT = 300.0f;
static constexpr float KHc = 15.0f, KVc = 0.1f;
static constexpr float OMEGAc = 7.29e-5f;
static constexpr float L_Vc = 2.5e6f;
static constexpr float R_GASc = 8.314f;
static constexpr float C_Pc = 1005.0f;
static constexpr float PTHc = 0.8f;
static constexpr float PYc  = (float)(3.14159265358979323846 * 6371000.0 / 33.0);
static constexpr float PXCc = (float)(2.0 * 3.14159265358979323846 * 6371000.0 / 64.0);
static constexpr float RCCc = (float)(0.7 * 5.67e-8 * 287.0 / (1005.0 * 100.0));
static constexpr float FBIG = 3.402823466e38f;

__constant__ float cDZ[13]  = {50,50,50,50,50,75,100,100,100,125,112,75,75};
__constant__ float cPRS[13] = {50,100,150,200,250,300,400,500,600,700,850,925,1000};

typedef short bf16x8 __attribute__((ext_vector_type(8)));
typedef float f32x4 __attribute__((ext_vector_type(4)));

DEVFN int pmh(int r){ return r < 0 ? r + 2 : (r > HH - 1 ? r - 2 : r); }
DEVFN int pmv(int r){ return r < 0 ? r + 2 : (r > VV - 1 ? r - 2 : r); }
DEVFN float latOf(int h){ return (90.0f - (float)(h + 1) * (180.0f / 33.0f)) * 0.017453292519943295f; }
DEVFN float avoid_inf(float t){
  if (t == 0.0f) t = 0.1f;
  if (fabsf(t) < 1.0f) t = copysignf(1.0f, t);
  return t;
}
DEVFN unsigned short f2bf(float f){
  unsigned u = __float_as_uint(f);
  unsigned r = (u + 0x7fffu + ((u >> 16) & 1u)) >> 16;
  return (unsigned short)r;
}

// ---- global-memory stencils on [B][13][32][64] ----
DEVFN float d_xf(const float* __restrict__ F, int rb, int w, float invpx){
  return (F[rb + ((w + 62) & 63)] - 8.f * F[rb + ((w + 63) & 63)]
        + 8.f * F[rb + ((w + 1) & 63)] - F[rb + ((w + 2) & 63)]) * (1.f / 12.f) * invpx;
}
DEVFN float d_yf(const float* __restrict__ F, int bvbase, int h, int w){
  return (-F[bvbase + pmh(h - 2) * 64 + w] + 8.f * F[bvbase + pmh(h - 1) * 64 + w]
          - 8.f * F[bvbase + pmh(h + 1) * 64 + w] + F[bvbase + pmh(h + 2) * 64 + w]) * (1.f / 12.f) * (1.f / PYc);
}
DEVFN float d_zf(const float* __restrict__ F, int bbase, int v, int hw){
  return (-F[bbase + pmv(v - 2) * 2048 + hw] + 8.f * F[bbase + pmv(v - 1) * 2048 + hw]
          - 8.f * F[bbase + pmv(v + 1) * 2048 + hw] + F[bbase + pmv(v + 2) * 2048 + hw]) * (1.f / 12.f) / cDZ[v];
}
DEVFN float dxxf(const float* __restrict__ F, int rb, int w, float invpx){
  float s = F[rb + ((w + 60) & 63)] - 16.f * F[rb + ((w + 61) & 63)] + 64.f * F[rb + ((w + 62) & 63)]
          + 16.f * F[rb + ((w + 63) & 63)] - 130.f * F[rb + w] + 16.f * F[rb + ((w + 1) & 63)]
          + 64.f * F[rb + ((w + 2) & 63)] - 16.f * F[rb + ((w + 3) & 63)] + F[rb + ((w + 4) & 63)];
  return s * (1.f / 144.f) * invpx * invpx;
}
DEVFN float dyyf(const float* __restrict__ F, int bvbase, int h, int w){
  float g0 = d_yf(F, bvbase, pmh(h - 2), w);
  float g1 = d_yf(F, bvbase, pmh(h - 1), w);
  float g2 = d_yf(F, bvbase, pmh(h + 1), w);
  float g3 = d_yf(F, bvbase, pmh(h + 2), w);
  return (-g0 + 8.f * g1 - 8.f * g2 + g3) * (1.f / 12.f) * (1.f / PYc);
}
DEVFN float dzzf(const float* __restrict__ F, int bbase, int v, int hw){
  float g0 = d_zf(F, bbase, pmv(v - 2), hw);
  float g1 = d_zf(F, bbase, pmv(v - 1), hw);
  float g2 = d_zf(F, bbase, pmv(v + 1), hw);
  float g3 = d_zf(F, bbase, pmv(v + 2), hw);
  return (-g0 + 8.f * g1 - 8.f * g2 + g3) * (1.f / 12.f) / cDZ[v];
}

// ---- LDS stencils on staged tile S[3][13][10][40] (flat) ----
#define SIDX(f,v,r,lw) (((f) * 13 + (v)) * 400 + (r) * 40 + (lw))
DEVFN float dyL(const float* S, int f, int v, int gr, int lw, int ra0){
  return (-S[SIDX(f, v, pmh(gr - 2) - ra0, lw)] + 8.f * S[SIDX(f, v, pmh(gr - 1) - ra0, lw)]
          - 8.f * S[SIDX(f, v, pmh(gr + 1) - ra0, lw)] + S[SIDX(f, v, pmh(gr + 2) - ra0, lw)]) * (1.f / 12.f) * (1.f / PYc);
}
DEVFN float dzL(const float* S, int f, int v, int r, int lw){
  return (-S[SIDX(f, pmv(v - 2), r, lw)] + 8.f * S[SIDX(f, pmv(v - 1), r, lw)]
          - 8.f * S[SIDX(f, pmv(v + 1), r, lw)] + S[SIDX(f, pmv(v + 2), r, lw)]) * (1.f / 12.f) / cDZ[v];
}
DEVFN float dxL(const float* S, int f, int v, int r, int lw, float invpx){
  int base = SIDX(f, v, r, lw);
  return (S[base - 2] - 8.f * S[base - 1] + 8.f * S[base + 1] - S[base + 2]) * (1.f / 12.f) * invpx;
}
DEVFN float dxxL(const float* S, int f, int v, int r, int lw, float invpx){
  int base = SIDX(f, v, r, lw);
  float s = S[base - 4] - 16.f * S[base - 3] + 64.f * S[base - 2] + 16.f * S[base - 1] - 130.f * S[base]
          + 16.f * S[base + 1] + 64.f * S[base + 2] - 16.f * S[base + 3] + S[base + 4];
  return s * (1.f / 144.f) * invpx * invpx;
}
DEVFN float dyyL(const float* S, int f, int v, int gr, int lw, int ra0){
  float g0 = dyL(S, f, v, pmh(gr - 2), lw, ra0);
  float g1 = dyL(S, f, v, pmh(gr - 1), lw, ra0);
  float g2 = dyL(S, f, v, pmh(gr + 1), lw, ra0);
  float g3 = dyL(S, f, v, pmh(gr + 2), lw, ra0);
  return (-g0 + 8.f * g1 - 8.f * g2 + g3) * (1.f / 12.f) * (1.f / PYc);
}
DEVFN float dzzL(const float* S, int f, int v, int r, int lw){
  float g0 = dzL(S, f, pmv(v - 2), r, lw);
  float g1 = dzL(S, f, pmv(v - 1), r, lw);
  float g2 = dzL(S, f, pmv(v + 1), r, lw);
  float g3 = dzL(S, f, pmv(v + 2), r, lw);
  return (-g0 + 8.f * g1 - 8.f * g2 + g3) * (1.f / 12.f) / cDZ[v];
}

// ---- reductions ----
DEVFN float waveRedSum(float v){ for (int o = 32; o; o >>= 1) v += __shfl_down(v, o, 64); return v; }
DEVFN float waveRedMin(float v){ for (int o = 32; o; o >>= 1) v = fminf(v, __shfl_down(v, o, 64)); return v; }
DEVFN float waveRedMax(float v){ for (int o = 32; o; o >>= 1) v = fmaxf(v, __shfl_down(v, o, 64)); return v; }

template<int OP, int NWV>
static __device__ float blockRedN(float v){
  __shared__ float s[NWV];
  v = OP == 0 ? waveRedSum(v) : OP == 1 ? waveRedMin(v) : waveRedMax(v);
  int lane = threadIdx.x & 63, wid = threadIdx.x >> 6;
  __syncthreads();
  if (lane == 0) s[wid] = v;
  __syncthreads();
  float r = s[0];
  #pragma unroll
  for (int k = 1; k < NWV; ++k)
    r = OP == 0 ? r + s[k] : OP == 1 ? fminf(r, s[k]) : fmaxf(r, s[k]);
  return r;
}

struct GB { const float* g[5]; const float* b[5]; };

// ================= launch 1: transpose x + pack both weights =================
__global__ void __launch_bounds__(256) pre_k(const float* __restrict__ x,
    const float* __restrict__ w1, const float* __restrict__ w2,
    unsigned short* __restrict__ XT, unsigned short* __restrict__ wp1,
    unsigned short* __restrict__ wp2)
{
  int blk = blockIdx.x, t = threadIdx.x;
  if (blk < 1024){
    __shared__ float tile[16 * 68];
    int zz = blk >> 8, rem = blk & 255;
    int b = rem >> 5, h = rem & 31;
    for (int p = zz * 4; p < zz * 4 + 4; ++p){
      int cbase = p * 16;
      __syncthreads();
      {
        int cl = t >> 4, w4 = (t & 15) * 4;
        float4 v = *(const float4*)(x + (((size_t)(b * 256 + cbase + cl) * 32 + h) * 64 + w4));
        tile[cl * 68 + w4 + 0] = v.x; tile[cl * 68 + w4 + 1] = v.y;
        tile[cl * 68 + w4 + 2] = v.z; tile[cl * 68 + w4 + 3] = v.w;
      }
      __syncthreads();
      {
        int w = t >> 2, c4 = (t & 3) * 4;
        ushort4 o;
        o.x = f2bf(tile[(c4 + 0) * 68 + w]);
        o.y = f2bf(tile[(c4 + 1) * 68 + w]);
        o.z = f2bf(tile[(c4 + 2) * 68 + w]);
        o.w = f2bf(tile[(c4 + 3) * 68 + w]);
        *(ushort4*)(XT + (((size_t)(b * 32 + h) * 64 + w) * 256 + cbase + c4)) = o;
      }
    }
  } else {
    const int T1 = 9 * 80 * 256;
    const int T2 = 9 * 256 * 96;
    int idx = (blk - 1024) * 256 + t;
    if (idx < T1){
      int dir = idx / (80 * 256);
      int r = idx - dir * (80 * 256);
      int co = r / 256, ci = r - co * 256;
      float v = (co < 65) ? w1[((size_t)(co * 256 + ci)) * 9 + dir] : 0.f;
      wp1[idx] = f2bf(v);
    } else if (idx < T1 + T2){
      int j = idx - T1;
      int dir = j / (256 * 96);
      int r = j - dir * (256 * 96);
      int co = r / 96, ci = r - co * 96;
      float v = (ci < 65) ? w2[((size_t)(co * 65 + ci)) * 9 + dir] : 0.f;
      wp2[j] = f2bf(v);
    }
  }
}

// ================= conv via MFMA; 32-pixel blocks; BN partials in epilogue =================
template<int CIT, int CIL, int CO, int COp, int NW, int MF, int SWZ>
__global__ void __launch_bounds__(NW * 64) conv_mfma_k(
    const unsigned short* __restrict__ XT, const unsigned short* __restrict__ Wp,
    const float* __restrict__ bias, float* __restrict__ out, float* __restrict__ bnp)
{
  __shared__ __align__(16) unsigned short Xl[3 * 34 * CIL];
  const int C8 = CIL / 8;
  int tid = threadIdx.x;
  int bx = blockIdx.x, b = blockIdx.y;
  int h = bx >> 1, p0 = (bx & 1) << 5;
  int bh = b * 64 + bx;
  int wid = tid >> 6, lane = tid & 63;
  int l15 = lane & 15, q = lane >> 4;

  f32x4 acc[MF][2];
  #pragma unroll
  for (int mf = 0; mf < MF; ++mf)
    #pragma unroll
    for (int nf = 0; nf < 2; ++nf){ f32x4 z = {0.f, 0.f, 0.f, 0.f}; acc[mf][nf] = z; }

  for (int cp = 0; cp < CIT / CIL; ++cp){
    if (cp) __syncthreads();
    for (int idx = tid; idx < 3 * 34 * C8; idx += NW * 64){
      int r = idx / (34 * C8);
      int rest = idx - r * (34 * C8);
      int j = rest / C8;
      int c8 = rest - j * C8;
      int hh = h + r - 1;
      int gw = p0 - 1 + j;
      uint4 val = make_uint4(0, 0, 0, 0);
      if (hh >= 0 && hh < 32 && gw >= 0 && gw < 64)
        val = *(const uint4*)(XT + (((size_t)(b * 32 + hh) * 64 + gw) * CIT + cp * CIL + c8 * 8));
      int dst = (r * 34 + j) * CIL + ((c8 * 8) ^ ((j & SWZ) << 3));
      *(uint4*)(Xl + dst) = val;
    }
    __syncthreads();

    for (int dir = 0; dir < 9; ++dir){
      int dy = dir / 3, dx = dir - dy * 3;
      #pragma unroll
      for (int kc = 0; kc < CIL / 32; ++kc){
        int kb = kc * 32 + q * 8;
        bf16x8 a[MF];
        #pragma unroll
        for (int mf = 0; mf < MF; ++mf){
          int co = wid * (MF * 16) + mf * 16 + l15;
          a[mf] = *(const bf16x8*)(Wp + ((size_t)(dir * COp + co) * CIT + cp * CIL + kb));
        }
        #pragma unroll
        for (int nf = 0; nf < 2; ++nf){
          int j = nf * 16 + l15 + dx;
          bf16x8 bfrag = *(const bf16x8*)(Xl + ((dy * 34 + j) * CIL + (kb ^ ((j & SWZ) << 3))));
          #pragma unroll
          for (int mf = 0; mf < MF; ++mf)
            acc[mf][nf] = __builtin_amdgcn_mfma_f32_16x16x32_bf16(a[mf], bfrag, acc[mf][nf], 0, 0, 0);
        }
      }
    }
  }
  #pragma unroll
  for (int mf = 0; mf < MF; ++mf){
    #pragma unroll
    for (int r = 0; r < 4; ++r){
      int co = wid * (MF * 16) + mf * 16 + q * 4 + r;
      if (CO != COp && co >= CO) continue;
      float bv = bias[co];
      float sv = 0.f, sq = 0.f;
      #pragma unroll
      for (int nf = 0; nf < 2; ++nf){
        int pix = nf * 16 + l15;
        float val = acc[mf][nf][r] + bv;
        out[(size_t)(b * CO + co) * 2048 + h * 64 + p0 + pix] = val;
        sv += val; sq += val * val;
      }
      #pragma unroll
      for (int off = 8; off; off >>= 1){
        sv += __shfl_xor(sv, off, 16);
        sq += __shfl_xor(sq, off, 16);
      }
      if (l15 == 0){
        bnp[((size_t)co * 512 + bh) * 2]     = sv;
        bnp[((size_t)co * 512 + bh) * 2 + 1] = sq;
      }
    }
  }
}

// ================= prep: BN1 finalize (redundant) + field prep, 6-way split =================
__global__ void __launch_bounds__(256) prep_k(const float* __restrict__ hb,
  const float* __restrict__ bnp1, GB gb,
  float* __restrict__ Fz, float* __restrict__ Fq, float* __restrict__ Fu,
  float* __restrict__ Fvf, float* __restrict__ Ft,
  float* __restrict__ zx, float* __restrict__ zy, float* __restrict__ zz,
  float* __restrict__ ux, float* __restrict__ vy, float* __restrict__ wv,
  float* __restrict__ partS)
{
  __shared__ float As[65], Bs[65];
  int blk = blockIdx.x, t = threadIdx.x;
  {
    int wvid = t >> 6, lane = t & 63;
    for (int ch = wvid; ch < 65; ch += 4){
      const float4* pp = (const float4*)(bnp1 + (size_t)ch * 1024) + lane * 4;
      float s = 0.f, sq = 0.f;
      #pragma unroll
      for (int k = 0; k < 4; ++k){ float4 v = pp[k]; s += v.x + v.z; sq += v.y + v.w; }
      s = waveRedSum(s); sq = waveRedSum(sq);
      if (!lane){
        float m = s * (1.f / 16384.f);
        float var = sq * (1.f / 16384.f) - m * m;
        float rstd = rsqrtf(var + 1e-5f);
        int f = ch / 13, k = ch - f * 13;
        float g = gb.g[f][k], bbv = gb.b[f][k];
        As[ch] = g * rstd; Bs[ch] = bbv - m * g * rstd;
      }
    }
  }
  __syncthreads();

  int part = blk >> 6;
  int col = ((blk & 63) << 8) | t;
  int b = col >> 11, p = col & 2047, h = p >> 6, w = p & 63;
  int hbase = b * 65 * NPLANE;
  auto hn = [&](int ch, int hh, int ww)->float {
    return hb[hbase + ch * 2048 + hh * 64 + ww] * As[ch] + Bs[ch];
  };
  int fb = (b * 13) * 2048 + p;
  float lat = latOf(h);
  float invpx = 1.0f / (PXCc * cosf(lat));
  int wm2 = (w + 62) & 63, wm1 = (w + 63) & 63, wpl1 = (w + 1) & 63, wpl2 = (w + 2) & 63;
  int hm2 = pmh(h - 2), hm1 = pmh(h - 1), hp1 = pmh(h + 1), hp2 = pmh(h + 2);
  float fmn = FBIG, fmx = -FBIG, fsm = 0.f, smn = FBIG, smx = -FBIG;
  if (part < 5){
    int ch0 = part * 13;
    float c[13];
    #pragma unroll
    for (int v = 0; v < 13; ++v) c[v] = hn(ch0 + v, h, w);
    float* Fdst = part == 0 ? Fz : part == 1 ? Fq : part == 2 ? Fu : part == 3 ? Fvf : Ft;
    #pragma unroll
    for (int v = 0; v < 13; ++v) Fdst[fb + v * 2048] = c[v];
    if (part == 0){
      #pragma unroll
      for (int v = 0; v < 13; ++v){
        zz[fb + v * 2048] = (-c[pmv(v - 2)] + 8.f * c[pmv(v - 1)] - 8.f * c[pmv(v + 1)] + c[pmv(v + 2)]) * (1.f / 12.f) / cDZ[v];
        float zxv = (hn(v, h, wm2) - 8.f * hn(v, h, wm1) + 8.f * hn(v, h, wpl1) - hn(v, h, wpl2)) * (1.f / 12.f) * invpx;
        float zyv = (-hn(v, hm2, w) + 8.f * hn(v, hm1, w) - 8.f * hn(v, hp1, w) + hn(v, hp2, w)) * (1.f / 12.f) * (1.f / PYc);
        zx[fb + v * 2048] = zxv; zy[fb + v * 2048] = zyv;
      }
    }
    if (part == 2){
      #pragma unroll
      for (int v = 0; v < 13; ++v){
        float uxv = (hn(26 + v, h, wm2) - 8.f * hn(26 + v, h, wm1) + 8.f * hn(26 + v, h, wpl1) - hn(26 + v, h, wpl2)) * (1.f / 12.f) * invpx;
        ux[fb + v * 2048] = uxv;
      }
    }
    if (part == 3){
      #pragma unroll
      for (int v = 0; v < 13; ++v){
        float vyv = (-hn(39 + v, hm2, w) + 8.f * hn(39 + v, hm1, w) - 8.f * hn(39 + v, hp1, w) + hn(39 + v, hp2, w)) * (1.f / 12.f) * (1.f / PYc);
        vy[fb + v * 2048] = vyv;
      }
    }
    if (part == 4){
      #pragma unroll
      for (int v = 0; v < 13; ++v){
        float tcc = c[v] - 273.15f;
        float arg = 17.67f * tcc / avoid_inf(tcc + 243.5f);
        smn = fminf(smn, arg); smx = fmaxf(smx, arg);
      }
    }
    #pragma unroll
    for (int v = 0; v < 13; ++v){ fmn = fminf(fmn, c[v]); fmx = fmaxf(fmx, c[v]); fsm += c[v]; }
  } else {
    float cum = 0.f;
    #pragma unroll
    for (int v = 0; v < 13; ++v){
      float uxv = (hn(26 + v, h, wm2) - 8.f * hn(26 + v, h, wm1) + 8.f * hn(26 + v, h, wpl1) - hn(26 + v, h, wpl2)) * (1.f / 12.f) * invpx;
      float vyv = (-hn(39 + v, hm2, w) + 8.f * hn(39 + v, hm1, w) - 8.f * hn(39 + v, hp1, w) + hn(39 + v, hp2, w)) * (1.f / 12.f) * (1.f / PYc);
      cum += cDZ[v] * (uxv + vyv);
      wv[fb + v * 2048] = -cum;
    }
  }
  float* pb = partS + blk * 17;
  float r;
  r = blockRedN<1,4>(smn); if (!t) pb[0] = r;
  r = blockRedN<2,4>(smx); if (!t) pb[1] = r;
  #pragma unroll
  for (int f = 0; f < 5; ++f){
    r = blockRedN<1,4>(part == f ? fmn : FBIG);  if (!t) pb[2 + f * 3] = r;
    r = blockRedN<2,4>(part == f ? fmx : -FBIG); if (!t) pb[3 + f * 3] = r;
    r = blockRedN<0,4>(part == f ? fsm : 0.f);   if (!t) pb[4 + f * 3] = r;
  }
}

// ===== fused RK stage pair via halo recompute =====
// PAIR=0: stages 1+2 (writes C0, Ub/Vb/Tb, duA=k1+2k2, qtA+pqt)
// PAIR=1: stages 3+4 (duA += 2k3+k4, k4t->zt integral+pzt, pduv/pdt)
// Block: (b, 2-row h-tile, 32-col w-tile). Stage-a on 10x40 halo region -> LDS.
template<int PAIR>
__global__ void __launch_bounds__(512) stpair_k(
  const float* __restrict__ Au, const float* __restrict__ Av, const float* __restrict__ At,
  const float* __restrict__ Fu, const float* __restrict__ Fvf, const float* __restrict__ Ft,
  const float* __restrict__ Fq,
  const float* __restrict__ ux, const float* __restrict__ vy,
  const float* __restrict__ zx, const float* __restrict__ zy,
  const float* __restrict__ wv, const float* __restrict__ zz,
  const float* __restrict__ partS,
  float* __restrict__ C0,
  float* __restrict__ Uo, float* __restrict__ Vo, float* __restrict__ To,
  float* __restrict__ duA, float* __restrict__ dvA, float* __restrict__ dtA,
  float* __restrict__ qtA, float* __restrict__ ztA,
  float* __restrict__ pduv, float* __restrict__ pdt, float* __restrict__ pqt,
  float* __restrict__ pzt)
{
  __shared__ float S[3 * 13 * 400];     // [3][13][10][40]
  __shared__ float Sk4[13 * 2 * 32];
  int blk = blockIdx.x, t = threadIdx.x;
  int b = blk >> 5, t5 = blk & 31;
  int h0 = (t5 & 15) << 1, w0 = (t5 >> 4) << 5;
  int ra0 = h0 - 4; if (ra0 < 0) ra0 = 0;
  int ra1 = h0 + 5; if (ra1 > 31) ra1 = 31;
  int nra = ra1 - ra0 + 1;
  int bbase = (b * 13) * 2048;

  float ss = 0.f, off = 0.f;
  if (PAIR == 0){
    float v0 = (t < 384) ? partS[t * 17] : FBIG;
    float v1 = (t < 384) ? partS[t * 17 + 1] : -FBIG;
    float smn = blockRedN<1,8>(v0);
    float smx = blockRedN<2,8>(v1);
    ss = (3.01f + 3.47f) / (smx - smn);
    off = -3.47f - smn * ss;
  }
  const float ca = (PAIR == 0) ? 0.5f * DT : DT;

  // ---- stage a over halo region ----
  int nA = nra * 40 * 13;
  #pragma unroll 1
  for (int e = t; e < nA; e += 512){
    int lw = e % 40;
    int rr = (e / 40) % nra;
    int v = e / (40 * nra);
    int gr = ra0 + rr;
    int gw = (w0 - 4 + lw) & 63;
    int bvbase = (b * 13 + v) * 2048;
    int rb = bvbase + gr * 64;
    int hw = gr * 64 + gw;
    int i = bvbase + hw;
    float lat = latOf(gr);
    float invpx = 1.0f / (PXCc * cosf(lat));
    float fcor = 2.0f * OMEGAc * sinf(lat);
    float wvi = wv[i];
    float Ui = Au[i], Vi = Av[i], Ti = At[i];
    float Fui = (PAIR == 0) ? Ui : Fu[i];
    float Fvi = (PAIR == 0) ? Vi : Fvf[i];
    float Fti = (PAIR == 0) ? Ti : Ft[i];

    float dyU = d_yf(Au, bvbase, gr, gw);
    float dzU = d_zf(Au, bbase, v, hw);
    float dxV = d_xf(Av, rb, gw, invpx);
    float dzV = d_zf(Av, bbase, v, hw);
    float mixU = KHc * (dxxf(Au, rb, gw, invpx) + dyyf(Au, bvbase, gr, gw)) + KVc * dzzf(Au, bbase, v, hw);
    float mixV = KHc * (dxxf(Av, rb, gw, invpx) + dyyf(Av, bvbase, gr, gw)) + KVc * dzzf(Av, bbase, v, hw);
    float ku = -Ui * ux[i] - Vi * dyU - wvi * dzU + fcor * Vi - zx[i] + mixU;
    float kv = -Ui * dxV - Vi * vy[i] - wvi * dzV - fcor * Ui - zy[i] + mixV;

    float C0i;
    if (PAIR == 0){
      float zzi = zz[i], qi = Fq[i];
      float rho = -1.0f / avoid_inf(zzi);
      float p = rho * R_GASc * Ti;
      float tcc = Ti - 273.15f;
      float arg = 17.67f * tcc / avoid_inf(tcc + 243.5f);
      float es = 6.112f * expf(arg * ss + off) * 100.0f;
      float qs = fmaxf(0.622f * es / avoid_inf(p - 0.378f * es), 1e-6f);
      float rh = qi / avoid_inf(qs);
      float rate = (rh > PTHc) ? (qi - PTHc * qs) * (1.0f / DT) : 0.0f;
      C0i = -(L_Vc + 1.0f) * zzi * wvi * (1.0f / C_Pc) + rate * (L_Vc / C_Pc);
      if (gr >= h0 && gr <= h0 + 1 && lw >= 4 && lw <= 35) C0[i] = C0i;
    } else {
      C0i = C0[i];
    }

    float dxT = d_xf(At, rb, gw, invpx);
    float dyT = d_yf(At, bvbase, gr, gw);
    float dzT = d_zf(At, bbase, v, hw);
    float mixT = KHc * (dxxf(At, rb, gw, invpx) + dyyf(At, bvbase, gr, gw)) + KVc * dzzf(At, bbase, v, hw);
    float ta = Ti + 273.15f;
    float t2 = ta * ta;
    float ta5 = t2 * t2 * ta;
    float rc = -RCCc * ta5 / cPRS[v];
    float kt = C0i - Fui * dxT - Fvi * dyT - wvi * dzT + mixT + rc;

    S[SIDX(0, v, rr, lw)] = Fui + ca * ku;
    S[SIDX(1, v, rr, lw)] = Fvi + ca * kv;
    S[SIDX(2, v, rr, lw)] = Fti + ca * kt;
  }
  __syncthreads();

  // ---- stage b over owner tile (2 x 32 x 13) ----
  float m0a = FBIG, m1a = -FBIG, m2a = FBIG, m3a = -FBIG, m4a = FBIG, m5a = -FBIG;
  float qmn = FBIG, qmx = -FBIG;
  #pragma unroll 1
  for (int e = t; e < 832; e += 512){
    int ww = e & 31;
    int r2 = (e >> 5) & 1;
    int v = e >> 6;
    int gr = h0 + r2;
    int lw = 4 + ww;
    int r = gr - ra0;
    int gw = w0 + ww;
    int bvbase = (b * 13 + v) * 2048;
    int rb = bvbase + gr * 64;
    int hw = gr * 64 + gw;
    int i = bvbase + hw;
    float lat = latOf(gr);
    float invpx = 1.0f / (PXCc * cosf(lat));
    float fcor = 2.0f * OMEGAc * sinf(lat);
    float wvi = wv[i];
    float Ui = S[SIDX(0, v, r, lw)], Vi = S[SIDX(1, v, r, lw)], Ti = S[SIDX(2, v, r, lw)];
    float Fui = Fu[i], Fvi = Fvf[i], Fti = Ft[i];

    float dyU = dyL(S, 0, v, gr, lw, ra0);
    float dzU = dzL(S, 0, v, r, lw);
    float dxV = dxL(S, 1, v, r, lw, invpx);
    float dzV = dzL(S, 1, v, r, lw);
    float mixU = KHc * (dxxL(S, 0, v, r, lw, invpx) + dyyL(S, 0, v, gr, lw, ra0)) + KVc * dzzL(S, 0, v, r, lw);
    float mixV = KHc * (dxxL(S, 1, v, r, lw, invpx) + dyyL(S, 1, v, gr, lw, ra0)) + KVc * dzzL(S, 1, v, r, lw);
    float ku = -Ui * ux[i] - Vi * dyU - wvi * dzU + fcor * Vi - zx[i] + mixU;
    float kv = -Ui * dxV - Vi * vy[i] - wvi * dzV - fcor * Ui - zy[i] + mixV;

    float C0i = C0[i];
    float dxT = dxL(S, 2, v, r, lw, invpx);
    float dyT = dyL(S, 2, v, gr, lw, ra0);
    float dzT = dzL(S, 2, v, r, lw);
    float mixT = KHc * (dxxL(S, 2, v, r, lw, invpx) + dyyL(S, 2, v, gr, lw, ra0)) + KVc * dzzL(S, 2, v, r, lw);
    float ta = Ti + 273.15f;
    float t2 = ta * ta;
    float ta5 = t2 * t2 * ta;
    float rc = -RCCc * ta5 / cPRS[v];
    float kt = C0i - Fui * dxT - Fvi * dyT - wvi * dzT + mixT + rc;

    if (PAIR == 0){
      // recover k1 from staged field; init accumulators; write stage-2 output fields
      float k1u = (Ui - Fui) * (2.0f / DT);
      float k1v = (Vi - Fvi) * (2.0f / DT);
      float k1t = (Ti - Fti) * (2.0f / DT);
      duA[i] = k1u + 2.f * ku;
      dvA[i] = k1v + 2.f * kv;
      dtA[i] = k1t + 2.f * kt;
      Uo[i] = Fui + 0.5f * DT * ku;
      Vo[i] = Fvi + 0.5f * DT * kv;
      To[i] = Fti + 0.5f * DT * kt;
      // q tendency (uses original fields; prr recomputed)
      float zzi = zz[i], qi = Fq[i];
      float rho = -1.0f / avoid_inf(zzi);
      float p = rho * R_GASc * Fti;
      float tcc = Fti - 273.15f;
      float arg = 17.67f * tcc / avoid_inf(tcc + 243.5f);
      float es = 6.112f * expf(arg * ss + off) * 100.0f;
      float qs = fmaxf(0.622f * es / avoid_inf(p - 0.378f * es), 1e-6f);
      float rh = qi / avoid_inf(qs);
      float rate = (rh > PTHc) ? (qi - PTHc * qs) * (1.0f / DT) : 0.0f;
      float qtv = -Fui * d_xf(Fq, rb, gw, invpx) - Fvi * d_yf(Fq, bvbase, gr, gw) - wvi * d_zf(Fq, bbase, v, hw)
                + KHc * (dxxf(Fq, rb, gw, invpx) + dyyf(Fq, bvbase, gr, gw)) + KVc * dzzf(Fq, bbase, v, hw) - rate;
      qtA[i] = qtv;
      qmn = fminf(qmn, qtv); qmx = fmaxf(qmx, qtv);
    } else {
      float k3u = (Ui - Fui) * (1.0f / DT);
      float k3v = (Vi - Fvi) * (1.0f / DT);
      float k3t = (Ti - Fti) * (1.0f / DT);
      float au = duA[i] + 2.f * k3u + ku;
      float av = dvA[i] + 2.f * k3v + kv;
      float at = dtA[i] + 2.f * k3t + kt;
      duA[i] = au; dvA[i] = av; dtA[i] = at;
      Sk4[(v * 2 + r2) * 32 + ww] = kt;
      m0a = fminf(m0a, au); m1a = fmaxf(m1a, au);
      m2a = fminf(m2a, av); m3a = fmaxf(m3a, av);
      m4a = fminf(m4a, at); m5a = fmaxf(m5a, at);
    }
  }

  if (PAIR == 0){
    float r0 = blockRedN<1,8>(qmn), r1 = blockRedN<2,8>(qmx);
    if (!t){ pqt[blk * 2] = r0; pqt[blk * 2 + 1] = r1; }
  } else {
    float r0 = blockRedN<1,8>(m0a), r1 = blockRedN<2,8>(m1a);
    float r2 = blockRedN<1,8>(m2a), r3 = blockRedN<2,8>(m3a);
    float r4 = blockRedN<1,8>(m4a), r5 = blockRedN<2,8>(m5a);
    if (!t){
      float* pp = pduv + blk * 4;
      pp[0] = r0; pp[1] = r1; pp[2] = r2; pp[3] = r3;
      pdt[blk * 2] = r4; pdt[blk * 2 + 1] = r5;
    }
    __syncthreads();
    // z-tendency integral over this block's 64 owner columns
    if (t < 64){
      int ww = t & 31, r2c = t >> 5;
      int gr = h0 + r2c, gw = w0 + ww;
      int fb = bbase + gr * 64 + gw;
      float cum = 0.f, mn = FBIG, mx = -FBIG;
      #pragma unroll
      for (int v = 0; v < 13; ++v){
        cum += cDZ[v] * (-R_GASc / cPRS[v]) * Sk4[(v * 2 + r2c) * 32 + ww];
        ztA[fb + v * 2048] = cum;
        mn = fminf(mn, cum); mx = fmaxf(mx, cum);
      }
      mn = waveRedMin(mn); mx = waveRedMax(mx);
      if (!t){ pzt[blk * 2] = mn; pzt[blk * 2 + 1] = mx; }
    }
  }
}

// ===== fused: redundant sc2 finalize + outmid (LDS tile) + bf16 transpose out =====
__global__ void __launch_bounds__(256) outmid_fused_k(
  const float* __restrict__ hb,
  const float* __restrict__ Fz, const float* __restrict__ Fq, const float* __restrict__ Fu,
  const float* __restrict__ Fvf, const float* __restrict__ Ft,
  const float* __restrict__ ztA, const float* __restrict__ qtA,
  const float* __restrict__ duA, const float* __restrict__ dvA, const float* __restrict__ dtA,
  const float* __restrict__ coef, const float* __restrict__ partS,
  const float* __restrict__ pduv, const float* __restrict__ pdt,
  const float* __restrict__ pqt, const float* __restrict__ pzt,
  unsigned short* __restrict__ MT)
{
  __shared__ float tileBig[65 * 66];
  int blk = blockIdx.x, t = threadIdx.x;

  float fmn[5] = {FBIG, FBIG, FBIG, FBIG, FBIG};
  float fmx[5] = {-FBIG, -FBIG, -FBIG, -FBIG, -FBIG};
  float fsm[5] = {0.f, 0.f, 0.f, 0.f, 0.f};
  #pragma unroll 1
  for (int r0 = t; r0 < 384; r0 += 256){
    const float* pr = partS + r0 * 17;
    #pragma unroll
    for (int f = 0; f < 5; ++f){
      fmn[f] = fminf(fmn[f], pr[2 + f * 3]);
      fmx[f] = fmaxf(fmx[f], pr[3 + f * 3]);
      fsm[f] += pr[4 + f * 3];
    }
  }
  #pragma unroll
  for (int f = 0; f < 5; ++f){
    fmn[f] = blockRedN<1,4>(fmn[f]);
    fmx[f] = blockRedN<2,4>(fmx[f]);
    fsm[f] = blockRedN<0,4>(fsm[f]);
  }
  // 256 partial rows each (one per thread)
  float dumn = pduv[t * 4],     dumx = pduv[t * 4 + 1];
  float dvmn = pduv[t * 4 + 2], dvmx = pduv[t * 4 + 3];
  float dtmn = pdt[t * 2],      dtmx = pdt[t * 2 + 1];
  float qmn = pqt[t * 2],       qmx = pqt[t * 2 + 1];
  float zmn = pzt[t * 2],       zmx = pzt[t * 2 + 1];
  dumn = blockRedN<1,4>(dumn); dumx = blockRedN<2,4>(dumx);
  dvmn = blockRedN<1,4>(dvmn); dvmx = blockRedN<2,4>(dvmx);
  dtmn = blockRedN<1,4>(dtmn); dtmx = blockRedN<2,4>(dtmx);
  qmn = blockRedN<1,4>(qmn);   qmx = blockRedN<2,4>(qmx);
  zmn = blockRedN<1,4>(zmn);   zmx = blockRedN<2,4>(zmx);

  float scf[5], off2[5];
  {
    float rmn[5] = {zmn, qmn, dumn, dvmn, dtmn};
    float rmx[5] = {zmx, qmx, dumx, dvmx, dtmx};
    float cfs[5] = {DT, DT, DT / 6.f, DT / 6.f, DT / 6.f};
    #pragma unroll
    for (int f = 0; f < 5; ++f){
      float mnf = fmn[f], mef = fsm[f] * (1.0f / (float)NF), mxf = fmx[f];
      float aa = (mnf - mef) * 0.05f, b2 = (mxf - mef) * 0.05f;
      float cf = cfs[f];
      float dmn = rmn[f] * cf, dmx = rmx[f] * cf;
      float s = (b2 - aa) / (dmx - dmn);
      scf[f] = s * cf; off2[f] = aa - dmn * s;
    }
  }

  int b = blk >> 5, h = blk & 31;
  #pragma unroll 1
  for (int idx = t; idx < 65 * 64; idx += 256){
    int c = idx >> 6, w = idx & 63;
    int f = c / 13, v = c - f * 13;
    int fi = (b * 13 + v) * 2048 + h * 64 + w;
    const float *Fp, *Rp;
    switch (f){
      case 0: Fp = Fz;  Rp = ztA; break;
      case 1: Fp = Fq;  Rp = qtA; break;
      case 2: Fp = Fu;  Rp = duA; break;
      case 3: Fp = Fvf; Rp = dvA; break;
      default: Fp = Ft; Rp = dtA; break;
    }
    float phys = Fp[fi] + Rp[fi] * scf[f] + off2[f];
    float cf = coef[c * 2048 + h * 64 + w];
    float hbv = hb[((size_t)(b * 65 + c)) * 2048 + h * 64 + w];
    tileBig[c * 66 + w] = cf * phys + (1.0f - cf) * hbv;
  }
  __syncthreads();
  #pragma unroll 1
  for (int ph = 0; ph < 6; ++ph){
    int cbase = ph * 16;
    int w = t >> 2, c4 = (t & 3) * 4;
    int c0 = cbase + c4;
    ushort4 o;
    o.x = (c0 + 0 < 65) ? f2bf(tileBig[(c0 + 0) * 66 + w]) : (unsigned short)0;
    o.y = (c0 + 1 < 65) ? f2bf(tileBig[(c0 + 1) * 66 + w]) : (unsigned short)0;
    o.z = (c0 + 2 < 65) ? f2bf(tileBig[(c0 + 2) * 66 + w]) : (unsigned short)0;
    o.w = (c0 + 3 < 65) ? f2bf(tileBig[(c0 + 3) * 66 + w]) : (unsigned short)0;
    *(ushort4*)(MT + (((size_t)(b * 32 + h) * 64 + w) * 96 + c0)) = o;
  }
}

// ===== final: redundant BN2 finalize + apply BN + residual =====
__global__ void __launch_bounds__(256) final_k(float* __restrict__ y, const float* __restrict__ x,
  const float* __restrict__ bnp2, const float* __restrict__ gblk, const float* __restrict__ bblk)
{
  int blk = blockIdx.x, t = threadIdx.x;
  int c = (blk >> 1) & 255;
  float4 pv = ((const float4*)(bnp2 + (size_t)c * 1024))[t];
  float s = pv.x + pv.z, sq = pv.y + pv.w;
  s = blockRedN<0,4>(s); sq = blockRedN<0,4>(sq);
  float m = s * (1.0f / 16384.0f);
  float var = sq * (1.0f / 16384.0f) - m * m;
  float rstd = rsqrtf(var + 1e-5f);
  float a = gblk[c] * rstd, bb = bblk[c] - m * gblk[c] * rstd;
  int e4 = blk * 256 + t;
  float4 v = ((const float4*)y)[e4];
  float4 xv = ((const float4*)x)[e4];
  v.x = v.x * a + bb + xv.x;
  v.y = v.y * a + bb + xv.y;
  v.z = v.z * a + bb + xv.z;
  v.w = v.w * a + bb + xv.w;
  ((float4*)y)[e4] = v;
}

extern "C" void kernel_launch(void* const* d_in, const int* in_sizes, int n_in,
                              void* d_out, int out_size, void* d_ws, size_t ws_size,
                              hipStream_t stream)
{
  (void)in_sizes; (void)n_in; (void)out_size; (void)ws_size;
  const float* x        = (const float*)d_in[0];
  const float* w_norm   = (const float*)d_in[1];
  const float* b_norm   = (const float*)d_in[2];
  const float* w_innorm = (const float*)d_in[3];
  const float* b_innorm = (const float*)d_in[4];
  const float* coef     = (const float*)d_in[5];
  GB gb;
  for (int f = 0; f < 5; ++f){
    gb.g[f] = (const float*)d_in[6 + 2 * f];
    gb.b[f] = (const float*)d_in[7 + 2 * f];
  }
  const float* gblk = (const float*)d_in[16];
  const float* bblk = (const float*)d_in[17];
  float* yout = (float*)d_out;

  float* ws = (float*)d_ws;
  size_t off = 0;
  auto alloc = [&](size_t n){ float* p = ws + off; off += n; return p; };
  float* hb  = alloc(NHB);
  float* Fz  = alloc(NF); float* Fq  = alloc(NF); float* Fu  = alloc(NF);
  float* Fvf = alloc(NF); float* Ft  = alloc(NF);
  float* zx  = alloc(NF); float* zy  = alloc(NF); float* zz  = alloc(NF);
  float* ux  = alloc(NF); float* vy  = alloc(NF); float* wvel = alloc(NF);
  float* C0  = alloc(NF); float* prr = alloc(NF);   // prr kept for layout (unused)
  float* Ua  = alloc(NF); float* Ub  = alloc(NF); float* Va  = alloc(NF); float* Vb = alloc(NF);
  float* Ta  = alloc(NF); float* Tb  = alloc(NF);
  float* duA = alloc(NF); float* dvA = alloc(NF); float* dtA = alloc(NF);
  float* k4t = alloc(NF);                           // unused (layout keeper)
  float* ztA = alloc(NF); float* qtA = alloc(NF);
  float* part1 = alloc(384 * 17 + 4);
  float* pduv = alloc(256 * 4); float* pdt = alloc(256 * 2);
  float* pqt  = alloc(256 * 2); float* pzt = alloc(256 * 2);
  float* bnp1 = alloc(65 * 512 * 2);
  float* bnp2 = alloc(256 * 512 * 2);
  float* Wp1f = alloc(9 * 80 * 256 / 2);
  float* Wp2f = alloc(9 * 256 * 96 / 2);
  unsigned short* Wp1 = (unsigned short*)Wp1f;
  unsigned short* Wp2 = (unsigned short*)Wp2f;
  (void)prr; (void)k4t; (void)Ua; (void)Va; (void)Ta;
  // XT bf16 (8 MB) aliases Ua..k4t (8.5 MB); dead after conv1. st12 writes Ub/Vb/Tb
  // (inside this span) only AFTER conv1+prep complete.
  unsigned short* XT = (unsigned short*)Ua;
  // MT bf16 (3.15 MB) aliases C0,prr,Ua,Ub (3.4 MB): C0 last read in st34, Ub last read
  // in st34; outmid (writer of MT) runs after st34, reads none of them.
  unsigned short* MT = (unsigned short*)C0;

  // 1. transpose x + pack both weights
  pre_k<<<2608, 256, 0, stream>>>(x, w_norm, w_innorm, XT, Wp1, Wp2);
  // 2. conv1 (bf16 MFMA, BN1 partials in epilogue)
  conv_mfma_k<256, 128, 65, 80, 5, 1, 7><<<dim3(64, 8), 5 * 64, 0, stream>>>(XT, Wp1, b_norm, hb, bnp1);
  // 3. prep (redundant BN1 finalize + 6-way field split + stat partials)
  prep_k<<<384, 256, 0, stream>>>(hb, bnp1, gb, Fz, Fq, Fu, Fvf, Ft, zx, zy, zz, ux, vy, wvel, part1);
  // 4. stages 1+2 fused (halo recompute)
  stpair_k<0><<<256, 512, 0, stream>>>(Fu, Fvf, Ft, Fu, Fvf, Ft, Fq, ux, vy, zx, zy, wvel, zz, part1,
      C0, Ub, Vb, Tb, duA, dvA, dtA, qtA, ztA, pduv, pdt, pqt, pzt);
  // 5. stages 3+4 fused (+ z-integral + all final partials)
  stpair_k<1><<<256, 512, 0, stream>>>(Ub, Vb, Tb, Fu, Fvf, Ft, Fq, ux, vy, zx, zy, wvel, zz, part1,
      C0, Ub, Vb, Tb, duA, dvA, dtA, qtA, ztA, pduv, pdt, pqt, pzt);
  // 6. fused finalize + outmid + bf16 transpose
  outmid_fused_k<<<256, 256, 0, stream>>>(hb, Fz, Fq, Fu, Fvf, Ft, ztA, qtA, duA, dvA, dtA,
      coef, part1, pduv, pdt, pqt, pzt, MT);
  // 7. conv2 (BN2 partials in epilogue)
  conv_mfma_k<96, 96, 256, 256, 8, 2, 3><<<dim3(64, 8), 8 * 64, 0, stream>>>(MT, Wp2, b_innorm, yout, bnp2);
  // 8. redundant BN2 finalize + apply + residual
  final_k<<<4096, 256, 0, stream>>>(yout, x, bnp2, gblk, bblk);
}

// Round 9
// 184.791 us; speedup vs baseline: 2.0983x; 2.0983x over previous
//
#include <hip/hip_runtime.h>
#include <math.h>

#define DEVFN static __device__ __forceinline__

static constexpr int BB = 8, VV = 13, HH = 32, WW = 64;
static constexpr int NPLANE = HH * WW;        // 2048
static constexpr int NF = BB * VV * NPLANE;   // 212992
static constexpr int NHB = BB * 65 * NPLANE;  // 1064960

static constexpr float DT = 300.0f;
static constexpr float KHc = 15.0f, KVc = 0.1f;
static constexpr float OMEGAc = 7.29e-5f;
static constexpr float L_Vc = 2.5e6f;
static constexpr float R_GASc = 8.314f;
static constexpr float C_Pc = 1005.0f;
static constexpr float PTHc = 0.8f;
static constexpr float PYc  = (float)(3.14159265358979323846 * 6371000.0 / 33.0);
static constexpr float PXCc = (float)(2.0 * 3.14159265358979323846 * 6371000.0 / 64.0);
static constexpr float RCCc = (float)(0.7 * 5.67e-8 * 287.0 / (1005.0 * 100.0));
static constexpr float FBIG = 3.402823466e38f;

__constant__ float cDZ[13]  = {50,50,50,50,50,75,100,100,100,125,112,75,75};
__constant__ float cPRS[13] = {50,100,150,200,250,300,400,500,600,700,850,925,1000};

typedef short bf16x8 __attribute__((ext_vector_type(8)));
typedef float f32x4 __attribute__((ext_vector_type(4)));

DEVFN int pmh(int r){ return r < 0 ? r + 2 : (r > HH - 1 ? r - 2 : r); }
DEVFN int pmv(int r){ return r < 0 ? r + 2 : (r > VV - 1 ? r - 2 : r); }
DEVFN float latOf(int h){ return (90.0f - (float)(h + 1) * (180.0f / 33.0f)) * 0.017453292519943295f; }
DEVFN float avoid_inf(float t){
  if (t == 0.0f) t = 0.1f;
  if (fabsf(t) < 1.0f) t = copysignf(1.0f, t);
  return t;
}
DEVFN unsigned short f2bf(float f){
  unsigned u = __float_as_uint(f);
  unsigned r = (u + 0x7fffu + ((u >> 16) & 1u)) >> 16;
  return (unsigned short)r;
}

// ---- global-memory stencils on [B][13][32][64] ----
DEVFN float d_xf(const float* __restrict__ F, int rb, int w, float invpx){
  return (F[rb + ((w + 62) & 63)] - 8.f * F[rb + ((w + 63) & 63)]
        + 8.f * F[rb + ((w + 1) & 63)] - F[rb + ((w + 2) & 63)]) * (1.f / 12.f) * invpx;
}
DEVFN float d_yf(const float* __restrict__ F, int bvbase, int h, int w){
  return (-F[bvbase + pmh(h - 2) * 64 + w] + 8.f * F[bvbase + pmh(h - 1) * 64 + w]
          - 8.f * F[bvbase + pmh(h + 1) * 64 + w] + F[bvbase + pmh(h + 2) * 64 + w]) * (1.f / 12.f) * (1.f / PYc);
}
DEVFN float d_zf(const float* __restrict__ F, int bbase, int v, int hw){
  return (-F[bbase + pmv(v - 2) * 2048 + hw] + 8.f * F[bbase + pmv(v - 1) * 2048 + hw]
          - 8.f * F[bbase + pmv(v + 1) * 2048 + hw] + F[bbase + pmv(v + 2) * 2048 + hw]) * (1.f / 12.f) / cDZ[v];
}
DEVFN float dxxf(const float* __restrict__ F, int rb, int w, float invpx){
  float s = F[rb + ((w + 60) & 63)] - 16.f * F[rb + ((w + 61) & 63)] + 64.f * F[rb + ((w + 62) & 63)]
          + 16.f * F[rb + ((w + 63) & 63)] - 130.f * F[rb + w] + 16.f * F[rb + ((w + 1) & 63)]
          + 64.f * F[rb + ((w + 2) & 63)] - 16.f * F[rb + ((w + 3) & 63)] + F[rb + ((w + 4) & 63)];
  return s * (1.f / 144.f) * invpx * invpx;
}
DEVFN float dyyf(const float* __restrict__ F, int bvbase, int h, int w){
  float g0 = d_yf(F, bvbase, pmh(h - 2), w);
  float g1 = d_yf(F, bvbase, pmh(h - 1), w);
  float g2 = d_yf(F, bvbase, pmh(h + 1), w);
  float g3 = d_yf(F, bvbase, pmh(h + 2), w);
  return (-g0 + 8.f * g1 - 8.f * g2 + g3) * (1.f / 12.f) * (1.f / PYc);
}
DEVFN float dzzf(const float* __restrict__ F, int bbase, int v, int hw){
  float g0 = d_zf(F, bbase, pmv(v - 2), hw);
  float g1 = d_zf(F, bbase, pmv(v - 1), hw);
  float g2 = d_zf(F, bbase, pmv(v + 1), hw);
  float g3 = d_zf(F, bbase, pmv(v + 2), hw);
  return (-g0 + 8.f * g1 - 8.f * g2 + g3) * (1.f / 12.f) / cDZ[v];
}

// ---- LDS stencils on staged [NFLD][12][64] plane rows (ra0-based) ----
DEVFN float SvF(const float* S, int f, int row, int ra0, int w){
  return S[(f * 12 + row - ra0) * 64 + (w & 63)];
}
DEVFN float dyS(const float* S, int f, int gr, int ra0, int w){
  return (-SvF(S, f, pmh(gr - 2), ra0, w) + 8.f * SvF(S, f, pmh(gr - 1), ra0, w)
          - 8.f * SvF(S, f, pmh(gr + 1), ra0, w) + SvF(S, f, pmh(gr + 2), ra0, w)) * (1.f / 12.f) * (1.f / PYc);
}
DEVFN float dyyS(const float* S, int f, int gr, int ra0, int w){
  float g0 = dyS(S, f, pmh(gr - 2), ra0, w);
  float g1 = dyS(S, f, pmh(gr - 1), ra0, w);
  float g2 = dyS(S, f, pmh(gr + 1), ra0, w);
  float g3 = dyS(S, f, pmh(gr + 2), ra0, w);
  return (-g0 + 8.f * g1 - 8.f * g2 + g3) * (1.f / 12.f) * (1.f / PYc);
}
DEVFN float dxS(const float* S, int f, int row, int ra0, int w, float invpx){
  int base = (f * 12 + row - ra0) * 64;
  return (S[base + ((w + 62) & 63)] - 8.f * S[base + ((w + 63) & 63)]
        + 8.f * S[base + ((w + 1) & 63)] - S[base + ((w + 2) & 63)]) * (1.f / 12.f) * invpx;
}
DEVFN float dxxS(const float* S, int f, int row, int ra0, int w, float invpx){
  int base = (f * 12 + row - ra0) * 64;
  float s = S[base + ((w + 60) & 63)] - 16.f * S[base + ((w + 61) & 63)] + 64.f * S[base + ((w + 62) & 63)]
          + 16.f * S[base + ((w + 63) & 63)] - 130.f * S[base + w] + 16.f * S[base + ((w + 1) & 63)]
          + 64.f * S[base + ((w + 2) & 63)] - 16.f * S[base + ((w + 3) & 63)] + S[base + ((w + 4) & 63)];
  return s * (1.f / 144.f) * invpx * invpx;
}

// ---- reductions ----
DEVFN float waveRedSum(float v){ for (int o = 32; o; o >>= 1) v += __shfl_down(v, o, 64); return v; }
DEVFN float waveRedMin(float v){ for (int o = 32; o; o >>= 1) v = fminf(v, __shfl_down(v, o, 64)); return v; }
DEVFN float waveRedMax(float v){ for (int o = 32; o; o >>= 1) v = fmaxf(v, __shfl_down(v, o, 64)); return v; }

template<int OP, int NWV>
static __device__ float blockRedN(float v){
  __shared__ float s[NWV];
  v = OP == 0 ? waveRedSum(v) : OP == 1 ? waveRedMin(v) : waveRedMax(v);
  int lane = threadIdx.x & 63, wid = threadIdx.x >> 6;
  __syncthreads();
  if (lane == 0) s[wid] = v;
  __syncthreads();
  float r = s[0];
  #pragma unroll
  for (int k = 1; k < NWV; ++k)
    r = OP == 0 ? r + s[k] : OP == 1 ? fminf(r, s[k]) : fmaxf(r, s[k]);
  return r;
}

struct GB { const float* g[5]; const float* b[5]; };

// ================= launch 1: transpose x + pack both weights =================
__global__ void __launch_bounds__(256) pre_k(const float* __restrict__ x,
    const float* __restrict__ w1, const float* __restrict__ w2,
    unsigned short* __restrict__ XT, unsigned short* __restrict__ wp1,
    unsigned short* __restrict__ wp2)
{
  int blk = blockIdx.x, t = threadIdx.x;
  if (blk < 1024){
    __shared__ float tile[16 * 68];
    int zz = blk >> 8, rem = blk & 255;
    int b = rem >> 5, h = rem & 31;
    for (int p = zz * 4; p < zz * 4 + 4; ++p){
      int cbase = p * 16;
      __syncthreads();
      {
        int cl = t >> 4, w4 = (t & 15) * 4;
        float4 v = *(const float4*)(x + (((size_t)(b * 256 + cbase + cl) * 32 + h) * 64 + w4));
        tile[cl * 68 + w4 + 0] = v.x; tile[cl * 68 + w4 + 1] = v.y;
        tile[cl * 68 + w4 + 2] = v.z; tile[cl * 68 + w4 + 3] = v.w;
      }
      __syncthreads();
      {
        int w = t >> 2, c4 = (t & 3) * 4;
        ushort4 o;
        o.x = f2bf(tile[(c4 + 0) * 68 + w]);
        o.y = f2bf(tile[(c4 + 1) * 68 + w]);
        o.z = f2bf(tile[(c4 + 2) * 68 + w]);
        o.w = f2bf(tile[(c4 + 3) * 68 + w]);
        *(ushort4*)(XT + (((size_t)(b * 32 + h) * 64 + w) * 256 + cbase + c4)) = o;
      }
    }
  } else {
    const int T1 = 9 * 80 * 256;
    const int T2 = 9 * 256 * 96;
    int idx = (blk - 1024) * 256 + t;
    if (idx < T1){
      int dir = idx / (80 * 256);
      int r = idx - dir * (80 * 256);
      int co = r / 256, ci = r - co * 256;
      float v = (co < 65) ? w1[((size_t)(co * 256 + ci)) * 9 + dir] : 0.f;
      wp1[idx] = f2bf(v);
    } else if (idx < T1 + T2){
      int j = idx - T1;
      int dir = j / (256 * 96);
      int r = j - dir * (256 * 96);
      int co = r / 96, ci = r - co * 96;
      float v = (ci < 65) ? w2[((size_t)(co * 65 + ci)) * 9 + dir] : 0.f;
      wp2[j] = f2bf(v);
    }
  }
}

// ================= conv via MFMA; 32-pixel blocks; BN partials in epilogue =================
template<int CIT, int CIL, int CO, int COp, int NW, int MF, int SWZ>
__global__ void __launch_bounds__(NW * 64) conv_mfma_k(
    const unsigned short* __restrict__ XT, const unsigned short* __restrict__ Wp,
    const float* __restrict__ bias, float* __restrict__ out, float* __restrict__ bnp)
{
  __shared__ __align__(16) unsigned short Xl[3 * 34 * CIL];
  const int C8 = CIL / 8;
  int tid = threadIdx.x;
  int bx = blockIdx.x, b = blockIdx.y;
  int h = bx >> 1, p0 = (bx & 1) << 5;
  int bh = b * 64 + bx;
  int wid = tid >> 6, lane = tid & 63;
  int l15 = lane & 15, q = lane >> 4;

  f32x4 acc[MF][2];
  #pragma unroll
  for (int mf = 0; mf < MF; ++mf)
    #pragma unroll
    for (int nf = 0; nf < 2; ++nf){ f32x4 z = {0.f, 0.f, 0.f, 0.f}; acc[mf][nf] = z; }

  for (int cp = 0; cp < CIT / CIL; ++cp){
    if (cp) __syncthreads();
    for (int idx = tid; idx < 3 * 34 * C8; idx += NW * 64){
      int r = idx / (34 * C8);
      int rest = idx - r * (34 * C8);
      int j = rest / C8;
      int c8 = rest - j * C8;
      int hh = h + r - 1;
      int gw = p0 - 1 + j;
      uint4 val = make_uint4(0, 0, 0, 0);
      if (hh >= 0 && hh < 32 && gw >= 0 && gw < 64)
        val = *(const uint4*)(XT + (((size_t)(b * 32 + hh) * 64 + gw) * CIT + cp * CIL + c8 * 8));
      int dst = (r * 34 + j) * CIL + ((c8 * 8) ^ ((j & SWZ) << 3));
      *(uint4*)(Xl + dst) = val;
    }
    __syncthreads();

    for (int dir = 0; dir < 9; ++dir){
      int dy = dir / 3, dx = dir - dy * 3;
      #pragma unroll
      for (int kc = 0; kc < CIL / 32; ++kc){
        int kb = kc * 32 + q * 8;
        bf16x8 a[MF];
        #pragma unroll
        for (int mf = 0; mf < MF; ++mf){
          int co = wid * (MF * 16) + mf * 16 + l15;
          a[mf] = *(const bf16x8*)(Wp + ((size_t)(dir * COp + co) * CIT + cp * CIL + kb));
        }
        #pragma unroll
        for (int nf = 0; nf < 2; ++nf){
          int j = nf * 16 + l15 + dx;
          bf16x8 bfrag = *(const bf16x8*)(Xl + ((dy * 34 + j) * CIL + (kb ^ ((j & SWZ) << 3))));
          #pragma unroll
          for (int mf = 0; mf < MF; ++mf)
            acc[mf][nf] = __builtin_amdgcn_mfma_f32_16x16x32_bf16(a[mf], bfrag, acc[mf][nf], 0, 0, 0);
        }
      }
    }
  }
  #pragma unroll
  for (int mf = 0; mf < MF; ++mf){
    #pragma unroll
    for (int r = 0; r < 4; ++r){
      int co = wid * (MF * 16) + mf * 16 + q * 4 + r;
      if (CO != COp && co >= CO) continue;
      float bv = bias[co];
      float sv = 0.f, sq = 0.f;
      #pragma unroll
      for (int nf = 0; nf < 2; ++nf){
        int pix = nf * 16 + l15;
        float val = acc[mf][nf][r] + bv;
        out[(size_t)(b * CO + co) * 2048 + h * 64 + p0 + pix] = val;
        sv += val; sq += val * val;
      }
      #pragma unroll
      for (int off = 8; off; off >>= 1){
        sv += __shfl_xor(sv, off, 16);
        sq += __shfl_xor(sq, off, 16);
      }
      if (l15 == 0){
        bnp[((size_t)co * 512 + bh) * 2]     = sv;
        bnp[((size_t)co * 512 + bh) * 2 + 1] = sq;
      }
    }
  }
}

// ================= prep: BN1 finalize (redundant) + field prep, 6-way split =================
__global__ void __launch_bounds__(256) prep_k(const float* __restrict__ hb,
  const float* __restrict__ bnp1, GB gb,
  float* __restrict__ Fz, float* __restrict__ Fq, float* __restrict__ Fu,
  float* __restrict__ Fvf, float* __restrict__ Ft,
  float* __restrict__ zx, float* __restrict__ zy, float* __restrict__ zz,
  float* __restrict__ ux, float* __restrict__ vy, float* __restrict__ wv,
  float* __restrict__ partS)
{
  __shared__ float As[65], Bs[65];
  int blk = blockIdx.x, t = threadIdx.x;
  {
    int wvid = t >> 6, lane = t & 63;
    for (int ch = wvid; ch < 65; ch += 4){
      const float4* pp = (const float4*)(bnp1 + (size_t)ch * 1024) + lane * 4;
      float s = 0.f, sq = 0.f;
      #pragma unroll
      for (int k = 0; k < 4; ++k){ float4 v = pp[k]; s += v.x + v.z; sq += v.y + v.w; }
      s = waveRedSum(s); sq = waveRedSum(sq);
      if (!lane){
        float m = s * (1.f / 16384.f);
        float var = sq * (1.f / 16384.f) - m * m;
        float rstd = rsqrtf(var + 1e-5f);
        int f = ch / 13, k = ch - f * 13;
        float g = gb.g[f][k], bbv = gb.b[f][k];
        As[ch] = g * rstd; Bs[ch] = bbv - m * g * rstd;
      }
    }
  }
  __syncthreads();

  int part = blk >> 6;
  int col = ((blk & 63) << 8) | t;
  int b = col >> 11, p = col & 2047, h = p >> 6, w = p & 63;
  int hbase = b * 65 * NPLANE;
  auto hn = [&](int ch, int hh, int ww)->float {
    return hb[hbase + ch * 2048 + hh * 64 + ww] * As[ch] + Bs[ch];
  };
  int fb = (b * 13) * 2048 + p;
  float lat = latOf(h);
  float invpx = 1.0f / (PXCc * cosf(lat));
  int wm2 = (w + 62) & 63, wm1 = (w + 63) & 63, wpl1 = (w + 1) & 63, wpl2 = (w + 2) & 63;
  int hm2 = pmh(h - 2), hm1 = pmh(h - 1), hp1 = pmh(h + 1), hp2 = pmh(h + 2);
  float fmn = FBIG, fmx = -FBIG, fsm = 0.f, smn = FBIG, smx = -FBIG;
  if (part < 5){
    int ch0 = part * 13;
    float c[13];
    #pragma unroll
    for (int v = 0; v < 13; ++v) c[v] = hn(ch0 + v, h, w);
    float* Fdst = part == 0 ? Fz : part == 1 ? Fq : part == 2 ? Fu : part == 3 ? Fvf : Ft;
    #pragma unroll
    for (int v = 0; v < 13; ++v) Fdst[fb + v * 2048] = c[v];
    if (part == 0){
      #pragma unroll
      for (int v = 0; v < 13; ++v){
        zz[fb + v * 2048] = (-c[pmv(v - 2)] + 8.f * c[pmv(v - 1)] - 8.f * c[pmv(v + 1)] + c[pmv(v + 2)]) * (1.f / 12.f) / cDZ[v];
        float zxv = (hn(v, h, wm2) - 8.f * hn(v, h, wm1) + 8.f * hn(v, h, wpl1) - hn(v, h, wpl2)) * (1.f / 12.f) * invpx;
        float zyv = (-hn(v, hm2, w) + 8.f * hn(v, hm1, w) - 8.f * hn(v, hp1, w) + hn(v, hp2, w)) * (1.f / 12.f) * (1.f / PYc);
        zx[fb + v * 2048] = zxv; zy[fb + v * 2048] = zyv;
      }
    }
    if (part == 2){
      #pragma unroll
      for (int v = 0; v < 13; ++v){
        float uxv = (hn(26 + v, h, wm2) - 8.f * hn(26 + v, h, wm1) + 8.f * hn(26 + v, h, wpl1) - hn(26 + v, h, wpl2)) * (1.f / 12.f) * invpx;
        ux[fb + v * 2048] = uxv;
      }
    }
    if (part == 3){
      #pragma unroll
      for (int v = 0; v < 13; ++v){
        float vyv = (-hn(39 + v, hm2, w) + 8.f * hn(39 + v, hm1, w) - 8.f * hn(39 + v, hp1, w) + hn(39 + v, hp2, w)) * (1.f / 12.f) * (1.f / PYc);
        vy[fb + v * 2048] = vyv;
      }
    }
    if (part == 4){
      #pragma unroll
      for (int v = 0; v < 13; ++v){
        float tcc = c[v] - 273.15f;
        float arg = 17.67f * tcc / avoid_inf(tcc + 243.5f);
        smn = fminf(smn, arg); smx = fmaxf(smx, arg);
      }
    }
    #pragma unroll
    for (int v = 0; v < 13; ++v){ fmn = fminf(fmn, c[v]); fmx = fmaxf(fmx, c[v]); fsm += c[v]; }
  } else {
    float cum = 0.f;
    #pragma unroll
    for (int v = 0; v < 13; ++v){
      float uxv = (hn(26 + v, h, wm2) - 8.f * hn(26 + v, h, wm1) + 8.f * hn(26 + v, h, wpl1) - hn(26 + v, h, wpl2)) * (1.f / 12.f) * invpx;
      float vyv = (-hn(39 + v, hm2, w) + 8.f * hn(39 + v, hm1, w) - 8.f * hn(39 + v, hp1, w) + hn(39 + v, hp2, w)) * (1.f / 12.f) * (1.f / PYc);
      cum += cDZ[v] * (uxv + vyv);
      wv[fb + v * 2048] = -cum;
    }
  }
  float* pb = partS + blk * 17;
  float r;
  r = blockRedN<1,4>(smn); if (!t) pb[0] = r;
  r = blockRedN<2,4>(smx); if (!t) pb[1] = r;
  #pragma unroll
  for (int f = 0; f < 5; ++f){
    r = blockRedN<1,4>(part == f ? fmn : FBIG);  if (!t) pb[2 + f * 3] = r;
    r = blockRedN<2,4>(part == f ? fmx : -FBIG); if (!t) pb[3 + f * 3] = r;
    r = blockRedN<0,4>(part == f ? fsm : 0.f);   if (!t) pb[4 + f * 3] = r;
  }
}

// ===== merged RK stage with LDS-staged own-plane rows =====
// Block = 4 rows x 64 w of one (b,v) plane; stages rows [h0-4, h0+7] of U,V,T(,Fq).
template<int STAGE>
__global__ void __launch_bounds__(256) stage_k(
  const float* __restrict__ U, const float* __restrict__ Vf, const float* __restrict__ T,
  const float* __restrict__ Fu, const float* __restrict__ Fvf, const float* __restrict__ Ft,
  const float* __restrict__ Fq,
  const float* __restrict__ ux, const float* __restrict__ vy,
  const float* __restrict__ zx, const float* __restrict__ zy,
  const float* __restrict__ wv, const float* __restrict__ zz,
  const float* __restrict__ partS,
  float* C0, float* prr,
  float* Uo, float* Vo, float* To,
  float* duA, float* dvA, float* dtA, float* k4t, float* qtA,
  float* pduv, float* pdt, float* pqt, float cnext)
{
  __shared__ float S[4 * 12 * 64];
  int blk = blockIdx.x, t = threadIdx.x;

  float ss = 0.f, off = 0.f;
  if (STAGE == 1){
    float v0 = partS[t * 17], v1 = partS[t * 17 + 1];
    if (t < 128){
      v0 = fminf(v0, partS[(t + 256) * 17]);
      v1 = fmaxf(v1, partS[(t + 256) * 17 + 1]);
    }
    float smn = blockRedN<1,4>(v0);
    float smx = blockRedN<2,4>(v1);
    ss = (3.01f + 3.47f) / (smx - smn);
    off = -3.47f - smn * ss;
  }

  int bv = blk >> 3;
  int h0 = (blk & 7) << 2;
  int ra0 = h0 - 4; if (ra0 < 0) ra0 = 0;
  int ra1 = h0 + 7; if (ra1 > 31) ra1 = 31;
  int nra = ra1 - ra0 + 1;
  int bvbase = bv * 2048;
  const int NFLD = (STAGE == 2) ? 4 : 3;
  #pragma unroll 1
  for (int e = t; e < NFLD * nra * 64; e += 256){
    int w = e & 63;
    int rf = e >> 6;
    int r = rf % nra;
    int f = rf / nra;
    const float* src = f == 0 ? U : f == 1 ? Vf : f == 2 ? T : Fq;
    S[(f * 12 + r) * 64 + w] = src[bvbase + (ra0 + r) * 64 + w];
  }
  __syncthreads();

  int i = blk * 256 + t;
  int w = t & 63, h = h0 + (t >> 6);
  int v = bv % 13;
  int bbase = (bv - v) * 2048;
  int hw = h * 64 + w;
  float lat = latOf(h);
  float invpx = 1.0f / (PXCc * cosf(lat));
  float fcor = 2.0f * OMEGAc * sinf(lat);
  float wvi = wv[i];
  float Ui = SvF(S, 0, h, ra0, w), Vi = SvF(S, 1, h, ra0, w), Ti = SvF(S, 2, h, ra0, w);
  float Fui = (STAGE == 1) ? Ui : Fu[i];
  float Fvi = (STAGE == 1) ? Vi : Fvf[i];

  float dyU = dyS(S, 0, h, ra0, w);
  float dzU = d_zf(U, bbase, v, hw);
  float dxV = dxS(S, 1, h, ra0, w, invpx);
  float dzV = d_zf(Vf, bbase, v, hw);
  float mixU = KHc * (dxxS(S, 0, h, ra0, w, invpx) + dyyS(S, 0, h, ra0, w)) + KVc * dzzf(U, bbase, v, hw);
  float mixV = KHc * (dxxS(S, 1, h, ra0, w, invpx) + dyyS(S, 1, h, ra0, w)) + KVc * dzzf(Vf, bbase, v, hw);
  float ku = -Ui * ux[i] - Vi * dyU - wvi * dzU + fcor * Vi - zx[i] + mixU;
  float kv = -Ui * dxV - Vi * vy[i] - wvi * dzV - fcor * Ui - zy[i] + mixV;

  float C0i;
  if (STAGE == 1){
    float zzi = zz[i], qi = Fq[i];
    float rho = -1.0f / avoid_inf(zzi);
    float p = rho * R_GASc * Ti;
    float tcc = Ti - 273.15f;
    float arg = 17.67f * tcc / avoid_inf(tcc + 243.5f);
    float es = 6.112f * expf(arg * ss + off) * 100.0f;
    float qs = fmaxf(0.622f * es / avoid_inf(p - 0.378f * es), 1e-6f);
    float rh = qi / avoid_inf(qs);
    float rate = (rh > PTHc) ? (qi - PTHc * qs) * (1.0f / DT) : 0.0f;
    prr[i] = rate;
    C0i = -(L_Vc + 1.0f) * zzi * wvi * (1.0f / C_Pc) + rate * (L_Vc / C_Pc);
    C0[i] = C0i;
  } else {
    C0i = C0[i];
  }

  float dxT = dxS(S, 2, h, ra0, w, invpx);
  float dyT = dyS(S, 2, h, ra0, w);
  float dzT = d_zf(T, bbase, v, hw);
  float mixT = KHc * (dxxS(S, 2, h, ra0, w, invpx) + dyyS(S, 2, h, ra0, w)) + KVc * dzzf(T, bbase, v, hw);
  float ta = Ti + 273.15f;
  float t2 = ta * ta;
  float ta5 = t2 * t2 * ta;
  float rc = -RCCc * ta5 / cPRS[v];
  float kt = C0i - Fui * dxT - Fvi * dyT - wvi * dzT + mixT + rc;

  if (STAGE == 1){ duA[i] = ku; dvA[i] = kv; dtA[i] = kt; }
  else if (STAGE < 4){ duA[i] += 2.f * ku; dvA[i] += 2.f * kv; dtA[i] += 2.f * kt; }
  else {
    float au = duA[i] + ku, av = dvA[i] + kv, at = dtA[i] + kt;
    duA[i] = au; dvA[i] = av; dtA[i] = at; k4t[i] = kt;
    float m0 = blockRedN<1,4>(au), m1 = blockRedN<2,4>(au);
    float m2 = blockRedN<1,4>(av), m3 = blockRedN<2,4>(av);
    float m4 = blockRedN<1,4>(at), m5 = blockRedN<2,4>(at);
    if (!t){
      float* pp = pduv + blk * 4;
      pp[0] = m0; pp[1] = m1; pp[2] = m2; pp[3] = m3;
      pdt[blk * 2] = m4; pdt[blk * 2 + 1] = m5;
    }
  }
  if (STAGE < 4){
    float Fti = (STAGE == 1) ? Ti : Ft[i];
    Uo[i] = Fui + cnext * ku;
    Vo[i] = Fvi + cnext * kv;
    To[i] = Fti + cnext * kt;
  }

  if (STAGE == 2){
    float qtv = -Fui * dxS(S, 3, h, ra0, w, invpx) - Fvi * dyS(S, 3, h, ra0, w) - wvi * d_zf(Fq, bbase, v, hw)
              + KHc * (dxxS(S, 3, h, ra0, w, invpx) + dyyS(S, 3, h, ra0, w)) + KVc * dzzf(Fq, bbase, v, hw) - prr[i];
    qtA[i] = qtv;
    float m0 = blockRedN<1,4>(qtv), m1 = blockRedN<2,4>(qtv);
    if (!t){ pqt[blk * 2] = m0; pqt[blk * 2 + 1] = m1; }
  }
}

__global__ void __launch_bounds__(64) zt_k(const float* __restrict__ k4t, float* __restrict__ zt, float* __restrict__ pmm)
{
  int col = blockIdx.x * 64 + threadIdx.x;
  int b = col >> 11, p = col & 2047;
  int fb = b * 13 * 2048 + p;
  float cum = 0.f, mn = FBIG, mx = -FBIG;
  #pragma unroll
  for (int v = 0; v < 13; ++v){
    cum += cDZ[v] * (-R_GASc / cPRS[v]) * k4t[fb + v * 2048];
    zt[fb + v * 2048] = cum;
    mn = fminf(mn, cum); mx = fmaxf(mx, cum);
  }
  mn = waveRedMin(mn); mx = waveRedMax(mx);
  if (!threadIdx.x){ pmm[blockIdx.x * 2] = mn; pmm[blockIdx.x * 2 + 1] = mx; }
}

// ===== fused: redundant sc2 finalize + outmid (LDS tile) + bf16 transpose out =====
__global__ void __launch_bounds__(256) outmid_fused_k(
  const float* __restrict__ hb,
  const float* __restrict__ Fz, const float* __restrict__ Fq, const float* __restrict__ Fu,
  const float* __restrict__ Fvf, const float* __restrict__ Ft,
  const float* __restrict__ ztA, const float* __restrict__ qtA,
  const float* __restrict__ duA, const float* __restrict__ dvA, const float* __restrict__ dtA,
  const float* __restrict__ coef, const float* __restrict__ partS,
  const float* __restrict__ pduv, const float* __restrict__ pdt,
  const float* __restrict__ pqt, const float* __restrict__ pzt,
  unsigned short* __restrict__ MT)
{
  __shared__ float tileBig[65 * 66];
  int blk = blockIdx.x, t = threadIdx.x;

  float fmn[5] = {FBIG, FBIG, FBIG, FBIG, FBIG};
  float fmx[5] = {-FBIG, -FBIG, -FBIG, -FBIG, -FBIG};
  float fsm[5] = {0.f, 0.f, 0.f, 0.f, 0.f};
  #pragma unroll 1
  for (int r0 = t; r0 < 384; r0 += 256){
    const float* pr = partS + r0 * 17;
    #pragma unroll
    for (int f = 0; f < 5; ++f){
      fmn[f] = fminf(fmn[f], pr[2 + f * 3]);
      fmx[f] = fmaxf(fmx[f], pr[3 + f * 3]);
      fsm[f] += pr[4 + f * 3];
    }
  }
  #pragma unroll
  for (int f = 0; f < 5; ++f){
    fmn[f] = blockRedN<1,4>(fmn[f]);
    fmx[f] = blockRedN<2,4>(fmx[f]);
    fsm[f] = blockRedN<0,4>(fsm[f]);
  }
  float dumn = FBIG, dumx = -FBIG, dvmn = FBIG, dvmx = -FBIG, dtmn = FBIG, dtmx = -FBIG;
  float qmn = FBIG, qmx = -FBIG;
  #pragma unroll 1
  for (int r0 = t; r0 < 832; r0 += 256){
    dumn = fminf(dumn, pduv[r0 * 4]);     dumx = fmaxf(dumx, pduv[r0 * 4 + 1]);
    dvmn = fminf(dvmn, pduv[r0 * 4 + 2]); dvmx = fmaxf(dvmx, pduv[r0 * 4 + 3]);
    dtmn = fminf(dtmn, pdt[r0 * 2]);      dtmx = fmaxf(dtmx, pdt[r0 * 2 + 1]);
    qmn = fminf(qmn, pqt[r0 * 2]);        qmx = fmaxf(qmx, pqt[r0 * 2 + 1]);
  }
  float zmn = pzt[t * 2], zmx = pzt[t * 2 + 1];
  dumn = blockRedN<1,4>(dumn); dumx = blockRedN<2,4>(dumx);
  dvmn = blockRedN<1,4>(dvmn); dvmx = blockRedN<2,4>(dvmx);
  dtmn = blockRedN<1,4>(dtmn); dtmx = blockRedN<2,4>(dtmx);
  qmn = blockRedN<1,4>(qmn);   qmx = blockRedN<2,4>(qmx);
  zmn = blockRedN<1,4>(zmn);   zmx = blockRedN<2,4>(zmx);

  float scf[5], off2[5];
  {
    float rmn[5] = {zmn, qmn, dumn, dvmn, dtmn};
    float rmx[5] = {zmx, qmx, dumx, dvmx, dtmx};
    float cfs[5] = {DT, DT, DT / 6.f, DT / 6.f, DT / 6.f};
    #pragma unroll
    for (int f = 0; f < 5; ++f){
      float mnf = fmn[f], mef = fsm[f] * (1.0f / (float)NF), mxf = fmx[f];
      float aa = (mnf - mef) * 0.05f, b2 = (mxf - mef) * 0.05f;
      float cf = cfs[f];
      float dmn = rmn[f] * cf, dmx = rmx[f] * cf;
      float s = (b2 - aa) / (dmx - dmn);
      scf[f] = s * cf; off2[f] = aa - dmn * s;
    }
  }

  int b = blk >> 5, h = blk & 31;
  #pragma unroll 1
  for (int idx = t; idx < 65 * 64; idx += 256){
    int c = idx >> 6, w = idx & 63;
    int f = c / 13, v = c - f * 13;
    int fi = (b * 13 + v) * 2048 + h * 64 + w;
    const float *Fp, *Rp;
    switch (f){
      case 0: Fp = Fz;  Rp = ztA; break;
      case 1: Fp = Fq;  Rp = qtA; break;
      case 2: Fp = Fu;  Rp = duA; break;
      case 3: Fp = Fvf; Rp = dvA; break;
      default: Fp = Ft; Rp = dtA; break;
    }
    float phys = Fp[fi] + Rp[fi] * scf[f] + off2[f];
    float cf = coef[c * 2048 + h * 64 + w];
    float hbv = hb[((size_t)(b * 65 + c)) * 2048 + h * 64 + w];
    tileBig[c * 66 + w] = cf * phys + (1.0f - cf) * hbv;
  }
  __syncthreads();
  #pragma unroll 1
  for (int ph = 0; ph < 6; ++ph){
    int cbase = ph * 16;
    int w = t >> 2, c4 = (t & 3) * 4;
    int c0 = cbase + c4;
    ushort4 o;
    o.x = (c0 + 0 < 65) ? f2bf(tileBig[(c0 + 0) * 66 + w]) : (unsigned short)0;
    o.y = (c0 + 1 < 65) ? f2bf(tileBig[(c0 + 1) * 66 + w]) : (unsigned short)0;
    o.z = (c0 + 2 < 65) ? f2bf(tileBig[(c0 + 2) * 66 + w]) : (unsigned short)0;
    o.w = (c0 + 3 < 65) ? f2bf(tileBig[(c0 + 3) * 66 + w]) : (unsigned short)0;
    *(ushort4*)(MT + (((size_t)(b * 32 + h) * 64 + w) * 96 + c0)) = o;
  }
}

// ===== final: redundant BN2 finalize + apply BN + residual =====
__global__ void __launch_bounds__(256) final_k(float* __restrict__ y, const float* __restrict__ x,
  const float* __restrict__ bnp2, const float* __restrict__ gblk, const float* __restrict__ bblk)
{
  int blk = blockIdx.x, t = threadIdx.x;
  int c = (blk >> 1) & 255;
  float4 pv = ((const float4*)(bnp2 + (size_t)c * 1024))[t];
  float s = pv.x + pv.z, sq = pv.y + pv.w;
  s = blockRedN<0,4>(s); sq = blockRedN<0,4>(sq);
  float m = s * (1.0f / 16384.0f);
  float var = sq * (1.0f / 16384.0f) - m * m;
  float rstd = rsqrtf(var + 1e-5f);
  float a = gblk[c] * rstd, bb = bblk[c] - m * gblk[c] * rstd;
  int e4 = blk * 256 + t;
  float4 v = ((const float4*)y)[e4];
  float4 xv = ((const float4*)x)[e4];
  v.x = v.x * a + bb + xv.x;
  v.y = v.y * a + bb + xv.y;
  v.z = v.z * a + bb + xv.z;
  v.w = v.w * a + bb + xv.w;
  ((float4*)y)[e4] = v;
}

extern "C" void kernel_launch(void* const* d_in, const int* in_sizes, int n_in,
                              void* d_out, int out_size, void* d_ws, size_t ws_size,
                              hipStream_t stream)
{
  (void)in_sizes; (void)n_in; (void)out_size; (void)ws_size;
  const float* x        = (const float*)d_in[0];
  const float* w_norm   = (const float*)d_in[1];
  const float* b_norm   = (const float*)d_in[2];
  const float* w_innorm = (const float*)d_in[3];
  const float* b_innorm = (const float*)d_in[4];
  const float* coef     = (const float*)d_in[5];
  GB gb;
  for (int f = 0; f < 5; ++f){
    gb.g[f] = (const float*)d_in[6 + 2 * f];
    gb.b[f] = (const float*)d_in[7 + 2 * f];
  }
  const float* gblk = (const float*)d_in[16];
  const float* bblk = (const float*)d_in[17];
  float* yout = (float*)d_out;

  float* ws = (float*)d_ws;
  size_t off = 0;
  auto alloc = [&](size_t n){ float* p = ws + off; off += n; return p; };
  float* hb  = alloc(NHB);
  float* Fz  = alloc(NF); float* Fq  = alloc(NF); float* Fu  = alloc(NF);
  float* Fvf = alloc(NF); float* Ft  = alloc(NF);
  float* zx  = alloc(NF); float* zy  = alloc(NF); float* zz  = alloc(NF);
  float* ux  = alloc(NF); float* vy  = alloc(NF); float* wvel = alloc(NF);
  float* C0  = alloc(NF); float* prr = alloc(NF);
  float* Ua  = alloc(NF); float* Ub  = alloc(NF); float* Va  = alloc(NF); float* Vb = alloc(NF);
  float* Ta  = alloc(NF); float* Tb  = alloc(NF);
  float* duA = alloc(NF); float* dvA = alloc(NF); float* dtA = alloc(NF);
  float* k4t = alloc(NF); float* ztA = alloc(NF); float* qtA = alloc(NF);
  float* part1 = alloc(384 * 17 + 4);
  float* pduv = alloc(832 * 4); float* pdt = alloc(832 * 2);
  float* pqt  = alloc(832 * 2); float* pzt = alloc(256 * 2);
  float* bnp1 = alloc(65 * 512 * 2);
  float* bnp2 = alloc(256 * 512 * 2);
  float* Wp1f = alloc(9 * 80 * 256 / 2);
  float* Wp2f = alloc(9 * 256 * 96 / 2);
  unsigned short* Wp1 = (unsigned short*)Wp1f;
  unsigned short* Wp2 = (unsigned short*)Wp2f;
  // XT bf16 (8 MB) aliases Ua..k4t (8.5 MB); dead after conv1, before stage1 writes Ua.
  unsigned short* XT = (unsigned short*)Ua;
  // MT bf16 (3.15 MB) aliases C0,prr,Ua,Ub (3.4 MB) — all dead after stage4;
  // outmid reads none of them.
  unsigned short* MT = (unsigned short*)C0;

  // 1. transpose x + pack both weights
  pre_k<<<2608, 256, 0, stream>>>(x, w_norm, w_innorm, XT, Wp1, Wp2);
  // 2. conv1 (bf16 MFMA, BN1 partials in epilogue)
  conv_mfma_k<256, 128, 65, 80, 5, 1, 7><<<dim3(64, 8), 5 * 64, 0, stream>>>(XT, Wp1, b_norm, hb, bnp1);
  // 3. prep (redundant BN1 finalize + 6-way field split + stat partials)
  prep_k<<<384, 256, 0, stream>>>(hb, bnp1, gb, Fz, Fq, Fu, Fvf, Ft, zx, zy, zz, ux, vy, wvel, part1);
  // 4-7. RK stages (LDS-staged x/y stencils)
  stage_k<1><<<NF / 256, 256, 0, stream>>>(Fu, Fvf, Ft, Fu, Fvf, Ft, Fq, ux, vy, zx, zy, wvel, zz, part1,
      C0, prr, Ua, Va, Ta, duA, dvA, dtA, k4t, qtA, pduv, pdt, pqt, 0.5f * DT);
  stage_k<2><<<NF / 256, 256, 0, stream>>>(Ua, Va, Ta, Fu, Fvf, Ft, Fq, ux, vy, zx, zy, wvel, zz, part1,
      C0, prr, Ub, Vb, Tb, duA, dvA, dtA, k4t, qtA, pduv, pdt, pqt, 0.5f * DT);
  stage_k<3><<<NF / 256, 256, 0, stream>>>(Ub, Vb, Tb, Fu, Fvf, Ft, Fq, ux, vy, zx, zy, wvel, zz, part1,
      C0, prr, Ua, Va, Ta, duA, dvA, dtA, k4t, qtA, pduv, pdt, pqt, DT);
  stage_k<4><<<NF / 256, 256, 0, stream>>>(Ua, Va, Ta, Fu, Fvf, Ft, Fq, ux, vy, zx, zy, wvel, zz, part1,
      C0, prr, Ub, Vb, Tb, duA, dvA, dtA, k4t, qtA, pduv, pdt, pqt, 0.f);
  // 8. z-tendency integral
  zt_k<<<256, 64, 0, stream>>>(k4t, ztA, pzt);
  // 9. fused finalize + outmid + bf16 transpose
  outmid_fused_k<<<256, 256, 0, stream>>>(hb, Fz, Fq, Fu, Fvf, Ft, ztA, qtA, duA, dvA, dtA,
      coef, part1, pduv, pdt, pqt, pzt, MT);
  // 10. conv2 (BN2 partials in epilogue)
  conv_mfma_k<96, 96, 256, 256, 8, 2, 3><<<dim3(64, 8), 8 * 64, 0, stream>>>(MT, Wp2, b_innorm, yout, bnp2);
  // 11. redundant BN2 finalize + apply + residual
  final_k<<<4096, 256, 0, stream>>>(yout, x, bnp2, gblk, bblk);
}